// Round 4
// baseline (786.985 us; speedup 1.0000x reference)
//
#include <hip/hip_runtime.h>
#include <stdint.h>

typedef unsigned short u16;
typedef __bf16 bf16x8 __attribute__((ext_vector_type(8)));
typedef float f32x4 __attribute__((ext_vector_type(4)));
typedef u16 u16x4 __attribute__((ext_vector_type(4)));
typedef u16 u16x8 __attribute__((ext_vector_type(8)));

__device__ __forceinline__ u16 f2b(float f) {  // fp32 -> bf16 bits, RNE
    unsigned u = __builtin_bit_cast(unsigned, f);
    u = u + 0x7FFFu + ((u >> 16) & 1u);
    return (u16)(u >> 16);
}
__device__ __forceinline__ float b2f(u16 b) {
    return __builtin_bit_cast(float, (unsigned)b << 16);
}

// async global->LDS, 16B per lane. LDS dest = wave-uniform base + lane*16.
// Global source address is per-lane — we exploit that for XOR-swizzled stores.
__device__ __forceinline__ void glds16(const u16* g, u16* l) {
    __builtin_amdgcn_global_load_lds(
        (const __attribute__((address_space(1))) void*)g,
        (__attribute__((address_space(3))) void*)l,
        16, 0, 0);
}

// ---------------------------------------------------------------- cast fp32->bf16
__global__ __launch_bounds__(256) void cast_bf16(const float* __restrict__ src,
                                                 u16* __restrict__ dst, int n) {
    int i = (blockIdx.x * 256 + threadIdx.x) * 4;
    if (i >= n) return;
    f32x4 v = *(const f32x4*)(src + i);
    u16x4 o;
    o.x = f2b(v.x); o.y = f2b(v.y); o.z = f2b(v.z); o.w = f2b(v.w);
    *(u16x4*)(dst + i) = o;
}

// ---------------------------------------------------------------- GEMM C = A * Bt^T
// 128x128 tile, BK=32, 256 threads (4 waves, each 64x64 = 4x4 mfma 16x16x32).
template <int OUT_BF16>
__global__ __launch_bounds__(256) void gemm_bt(const u16* __restrict__ A,
                                               const u16* __restrict__ Bt,
                                               void* __restrict__ Cout,
                                               int M, int N, int K) {
    __shared__ u16 As[128 * 32];
    __shared__ u16 Bs[128 * 32];
    const int tid  = threadIdx.x;
    const int w    = tid >> 6;
    const int lane = tid & 63;
    const int quad = lane >> 4;
    const int ml   = lane & 15;
    const long bm  = (long)blockIdx.y * 128;
    const long bn  = (long)blockIdx.x * 128;
    const int wm   = (w >> 1) * 64;
    const int wn   = (w & 1) * 64;
    const int grow = lane >> 2;        // 0..15
    const int gcol = (lane & 3) * 8;   // 0,8,16,24

    const u16* Ag = A  + (bm + w * 16 + grow) * (long)K + gcol;
    const u16* Bg = Bt + (bn + w * 16 + grow) * (long)K + gcol;
    u16* lAs0 = &As[(w * 16) * 32];
    u16* lAs1 = &As[(64 + w * 16) * 32];
    u16* lBs0 = &Bs[(w * 16) * 32];
    u16* lBs1 = &Bs[(64 + w * 16) * 32];

    const f32x4 fz = {0.f, 0.f, 0.f, 0.f};
    f32x4 acc[4][4];
#pragma unroll
    for (int i = 0; i < 4; ++i)
#pragma unroll
        for (int j = 0; j < 4; ++j) acc[i][j] = fz;

    for (int k0 = 0; k0 < K; k0 += 32) {
        __syncthreads();
        glds16(Ag + k0,               lAs0);
        glds16(Ag + 64 * (long)K + k0, lAs1);
        glds16(Bg + k0,               lBs0);
        glds16(Bg + 64 * (long)K + k0, lBs1);
        __builtin_amdgcn_s_waitcnt(0);
        __syncthreads();
        bf16x8 af[4], bfr[4];
#pragma unroll
        for (int mt = 0; mt < 4; ++mt)
            af[mt] = *(const bf16x8*)&As[(wm + mt * 16 + ml) * 32 + quad * 8];
#pragma unroll
        for (int nt = 0; nt < 4; ++nt)
            bfr[nt] = *(const bf16x8*)&Bs[(wn + nt * 16 + ml) * 32 + quad * 8];
#pragma unroll
        for (int mt = 0; mt < 4; ++mt)
#pragma unroll
            for (int nt = 0; nt < 4; ++nt)
                acc[mt][nt] = __builtin_amdgcn_mfma_f32_16x16x32_bf16(
                    af[mt], bfr[nt], acc[mt][nt], 0, 0, 0);
    }
#pragma unroll
    for (int mt = 0; mt < 4; ++mt)
#pragma unroll
        for (int nt = 0; nt < 4; ++nt)
#pragma unroll
            for (int r = 0; r < 4; ++r) {
                long row = bm + wm + mt * 16 + quad * 4 + r;
                long col = bn + wn + nt * 16 + ml;
                float v = acc[mt][nt][r];
                if (OUT_BF16) ((u16*)Cout)[row * N + col] = f2b(v);
                else          ((float*)Cout)[row * N + col] = v;
            }
}

// ---------------------------------------------------------------- RMSNorm + RoPE + relayout
// q output pre-scaled by 1/sqrt(HEAD_DIM) = 2^-4 (exact in bf16).
__global__ __launch_bounds__(64) void norm_rope(const u16* __restrict__ qgk,
                                                const float* __restrict__ cosp,
                                                const float* __restrict__ sinp,
                                                const float* __restrict__ qw,
                                                const float* __restrict__ kw,
                                                u16* __restrict__ qf,
                                                u16* __restrict__ kf) {
    const int t = blockIdx.x;      // token = b*2048 + s
    const int u = blockIdx.y;
    const int lane = threadIdx.x;
    const int b = t >> 11, s = t & 2047;
    const u16* src; const float* wgt; u16* dst;
    if (u < 16) {
        src = qgk + (long)t * 8704 + u * 512;
        wgt = qw;
        dst = qf + ((long)(b * 16 + u) * 2048 + s) * 256;
    } else {
        int kh = u - 16;
        src = qgk + (long)t * 8704 + 8192 + kh * 256;
        wgt = kw;
        dst = kf + ((long)(b * 2 + kh) * 2048 + s) * 256;
    }
    const int d0 = lane * 4;
    u16x4 raw = *(const u16x4*)(src + d0);
    float x0 = b2f(raw.x), x1 = b2f(raw.y), x2 = b2f(raw.z), x3 = b2f(raw.w);
    float ss = x0 * x0 + x1 * x1 + x2 * x2 + x3 * x3;
    for (int off = 32; off; off >>= 1) ss += __shfl_xor(ss, off, 64);
    float inv = rsqrtf(ss * (1.0f / 256.0f) + 1e-6f);
    float n0 = x0 * inv * wgt[d0 + 0];
    float n1 = x1 * inv * wgt[d0 + 1];
    float n2 = x2 * inv * wgt[d0 + 2];
    float n3 = x3 * inv * wgt[d0 + 3];
    float p0 = __shfl_xor(n0, 8, 64);
    float p1 = __shfl_xor(n1, 8, 64);
    float p2 = __shfl_xor(n2, 8, 64);
    float p3 = __shfl_xor(n3, 8, 64);
    if (lane < 16) {
        f32x4 c  = *(const f32x4*)(cosp + (long)t * 64 + d0);
        f32x4 sn = *(const f32x4*)(sinp + (long)t * 64 + d0);
        float sgn = (lane < 8) ? -1.f : 1.f;
        n0 = n0 * c[0] + sgn * p0 * sn[0];
        n1 = n1 * c[1] + sgn * p1 * sn[1];
        n2 = n2 * c[2] + sgn * p2 * sn[2];
        n3 = n3 * c[3] + sgn * p3 * sn[3];
    }
    const float qs = (u < 16) ? 0.0625f : 1.0f;  // fold 1/sqrt(256) into q
    n0 *= qs; n1 *= qs; n2 *= qs; n3 *= qs;
    u16x4 o;
    o.x = f2b(n0); o.y = f2b(n1); o.z = f2b(n2); o.w = f2b(n3);
    *(u16x4*)(dst + d0) = o;
}

// ---------------------------------------------------------------- flash attention + gate
// Block = 128 q-rows (4 waves x 32 rows), 64-key tiles, fixed-shift softmax.
// K/V staged via global_load_lds with XOR-swizzled per-lane GLOBAL addresses:
// LDS row r stores logical 16B-chunk c at slot c^(r&7)  -> unpadded layout,
// bank-even ds_read_b128. P overlaps Ks (dead after QK; barrier in between).
// LDS = 64 KB exactly -> 2 blocks/CU.
__global__ __launch_bounds__(256, 2) void attn_fused(const u16* __restrict__ qf,
                                                     const u16* __restrict__ kf,
                                                     const u16* __restrict__ vt,
                                                     const u16* __restrict__ qgk,
                                                     u16* __restrict__ attn_g) {
    __shared__ u16 Ks[64 * 256];   // [key][d], 512B rows, swizzled, 32 KB
    __shared__ u16 Vt[256 * 64];   // [d][key], 128B rows, swizzled, 32 KB
    u16* Pb = Ks;                  // P: 128 rows x 88 u16 = 22.5 KB, overlaps Ks
    const int flat = blockIdx.x;
    const int qt = 15 - (flat >> 5);   // LPT: biggest q-tiles first
    const int h  = flat & 15;
    const int b  = (flat >> 4) & 1;
    const int kh = h >> 3;             // GQA rep = 8
    const int tid = threadIdx.x;
    const int w = tid >> 6, lane = tid & 63;
    const int quad = lane >> 4, ml = lane & 15;
    const int qbase = qt * 128;

    // Q fragments: 2 mt x 8 dd (wave owns rows qbase + w*32 + mt*16 + [0,16))
    bf16x8 qfrag[2][8];
#pragma unroll
    for (int mt = 0; mt < 2; ++mt) {
        const u16* qp = qf + ((long)(b * 16 + h) * 2048 + qbase + w * 32 + mt * 16 + ml) * 256;
#pragma unroll
        for (int dd = 0; dd < 8; ++dd)
            qfrag[mt][dd] = *(const bf16x8*)(qp + dd * 32 + quad * 8);
    }

    const f32x4 fz = {0.f, 0.f, 0.f, 0.f};
    f32x4 oacc[2][16];
#pragma unroll
    for (int mt = 0; mt < 2; ++mt)
#pragma unroll
        for (int i = 0; i < 16; ++i) oacc[mt][i] = fz;
    float lsum[2][4] = {{0.f,0.f,0.f,0.f},{0.f,0.f,0.f,0.f}};

    const u16* kbp = kf + (long)(b * 2 + kh) * 2048 * 256;
    const long vbase = (long)kh * 256 * 4096 + (long)b * 2048;

    const int nkt = 2 * qt + 2;  // causal: 64-key tiles 0..2qt+1
    for (int kt = 0; kt < nkt; ++kt) {
        const int kb = kt * 64;
        __syncthreads();   // prev iter's P/Vt reads complete everywhere
        // ---- stage K and V (each wave: 8 K-segments + 8 V-segments of 1 KB)
#pragma unroll
        for (int i = 0; i < 8; ++i) {
            int s = w * 8 + i;
            {   // K segment s: local keys 2s, 2s+1
                int keyl = 2 * s + (lane >> 5);
                int c = (lane & 31) ^ (keyl & 7);
                glds16(kbp + (long)(kb + keyl) * 256 + c * 8, &Ks[s * 512]);
            }
            {   // V segment s: d rows 8s..8s+7
                int dl = 8 * s + (lane >> 3);
                int c = (lane & 7) ^ (dl & 7);
                glds16(vt + vbase + (long)dl * 4096 + kb + c * 8, &Vt[s * 512]);
            }
        }
        __builtin_amdgcn_s_waitcnt(0);
        __syncthreads();   // tiles visible

        // ---- S = Q K^T : 2 mt x 4 nt tiles, K fragments shared across mt
        f32x4 sacc[2][4];
#pragma unroll
        for (int mt = 0; mt < 2; ++mt)
#pragma unroll
            for (int nt = 0; nt < 4; ++nt) sacc[mt][nt] = fz;
#pragma unroll
        for (int dd = 0; dd < 8; ++dd) {
#pragma unroll
            for (int nt = 0; nt < 4; ++nt) {
                bf16x8 kfr = *(const bf16x8*)&Ks[(nt * 16 + ml) * 256 +
                                                 (((dd * 4 + quad) ^ (ml & 7)) * 8)];
                sacc[0][nt] = __builtin_amdgcn_mfma_f32_16x16x32_bf16(qfrag[0][dd], kfr, sacc[0][nt], 0, 0, 0);
                sacc[1][nt] = __builtin_amdgcn_mfma_f32_16x16x32_bf16(qfrag[1][dd], kfr, sacc[1][nt], 0, 0, 0);
            }
        }
        __syncthreads();   // ALL waves done reading Ks before P overwrites it

        // ---- fixed-shift softmax: p = exp(s-16); |s|<=16 by RMS-norm construction
#pragma unroll
        for (int mt = 0; mt < 2; ++mt) {
            const int base_mt = qbase + w * 32 + mt * 16;
            const int prow = (w * 32 + mt * 16 + quad * 4) * 88;
            if (kb + 63 > base_mt) {   // tile touches/crosses the diagonal
#pragma unroll
                for (int nt = 0; nt < 4; ++nt)
#pragma unroll
                    for (int r = 0; r < 4; ++r) {
                        int col = kb + nt * 16 + ml;
                        int row = base_mt + quad * 4 + r;
                        float sv = (col > row) ? -1e30f : sacc[mt][nt][r];
                        float pv = __expf(sv - 16.0f);
                        lsum[mt][r] += pv;
                        Pb[prow + r * 88 + nt * 16 + ml] = f2b(pv);
                    }
            } else {
#pragma unroll
                for (int nt = 0; nt < 4; ++nt)
#pragma unroll
                    for (int r = 0; r < 4; ++r) {
                        float pv = __expf(sacc[mt][nt][r] - 16.0f);
                        lsum[mt][r] += pv;
                        Pb[prow + r * 88 + nt * 16 + ml] = f2b(pv);
                    }
            }
        }

        // ---- O += P V  (P rows wave-private; Vt stable until next stage)
#pragma unroll
        for (int ks = 0; ks < 2; ++ks) {
            bf16x8 pf0 = *(const bf16x8*)&Pb[(w * 32 + ml) * 88 + ks * 32 + quad * 8];
            bf16x8 pf1 = *(const bf16x8*)&Pb[(w * 32 + 16 + ml) * 88 + ks * 32 + quad * 8];
#pragma unroll
            for (int dt = 0; dt < 16; ++dt) {
                bf16x8 vfr = *(const bf16x8*)&Vt[(dt * 16 + ml) * 64 +
                                                 (((ks * 4 + quad) ^ (ml & 7)) * 8)];
                oacc[0][dt] = __builtin_amdgcn_mfma_f32_16x16x32_bf16(pf0, vfr, oacc[0][dt], 0, 0, 0);
                oacc[1][dt] = __builtin_amdgcn_mfma_f32_16x16x32_bf16(pf1, vfr, oacc[1][dt], 0, 0, 0);
            }
        }
    }

    // ---- deferred row-sum reduction (16 lanes of each quad-row group)
#pragma unroll
    for (int off = 1; off < 16; off <<= 1)
#pragma unroll
        for (int mt = 0; mt < 2; ++mt)
#pragma unroll
            for (int r = 0; r < 4; ++r) lsum[mt][r] += __shfl_xor(lsum[mt][r], off, 64);
    float invl[2][4];
#pragma unroll
    for (int mt = 0; mt < 2; ++mt)
#pragma unroll
        for (int r = 0; r < 4; ++r) invl[mt][r] = __builtin_amdgcn_rcpf(lsum[mt][r]);

    // ---- epilogue: sigmoid gate, store bf16 (4096 x 4096, col = h*256+d)
#pragma unroll
    for (int mt = 0; mt < 2; ++mt)
#pragma unroll
        for (int dt = 0; dt < 16; ++dt)
#pragma unroll
            for (int r = 0; r < 4; ++r) {
                int srow = qbase + w * 32 + mt * 16 + quad * 4 + r;
                long tok = (long)b * 2048 + srow;
                int d = dt * 16 + ml;
                float o = oacc[mt][dt][r] * invl[mt][r];
                float g = b2f(qgk[tok * 8704 + h * 512 + 256 + d]);
                float gv = o * __builtin_amdgcn_rcpf(1.f + __expf(-g));
                attn_g[tok * 4096 + h * 256 + d] = f2b(gv);
            }
}

// ---------------------------------------------------------------- launch
extern "C" void kernel_launch(void* const* d_in, const int* in_sizes, int n_in,
                              void* d_out, int out_size, void* d_ws, size_t ws_size,
                              hipStream_t stream) {
    (void)in_sizes; (void)n_in; (void)out_size;
    const float* hidden = (const float*)d_in[0];
    const float* cosp   = (const float*)d_in[1];
    const float* sinp   = (const float*)d_in[2];
    const float* Wq     = (const float*)d_in[3];
    const float* Wk     = (const float*)d_in[4];
    const float* Wv     = (const float*)d_in[5];
    const float* Wo     = (const float*)d_in[6];
    const float* qw     = (const float*)d_in[7];
    const float* kw     = (const float*)d_in[8];
    float* out = (float*)d_out;

    char* p = (char*)d_ws;
    u16* h_bf   = (u16*)p; p += (size_t)8388608 * 2;   // hidden bf16 (4096x2048)
    u16* Wqk_bf = (u16*)p; p += (size_t)17825792 * 2;  // Wq||Wk (8704x2048)
    u16* Wv_bf  = (u16*)p; p += (size_t)1048576 * 2;   // Wv (512x2048)
    u16* Wo_bf  = (u16*)p; p += (size_t)8388608 * 2;   // Wo (2048x4096)
    u16* qgk    = (u16*)p; p += (size_t)35651584 * 2;  // (4096x8704)
    u16* v_t    = (u16*)p; p += (size_t)2097152 * 2;   // V^T (512x4096)
    u16* q_f    = (u16*)p; p += (size_t)16777216 * 2;  // (2,16,2048,256)
    u16* k_f    = (u16*)p; p += (size_t)2097152 * 2;   // (2,2,2048,256)
    u16* attn_g = (u16*)p; p += (size_t)16777216 * 2;  // (4096x4096)
    if ((size_t)(p - (char*)d_ws) > ws_size) return;   // ws too small: leave output zero

    cast_bf16<<<8192,  256, 0, stream>>>(hidden, h_bf, 8388608);
    cast_bf16<<<16384, 256, 0, stream>>>(Wq, Wqk_bf, 16777216);
    cast_bf16<<<1024,  256, 0, stream>>>(Wk, Wqk_bf + (size_t)8192 * 2048, 1048576);
    cast_bf16<<<1024,  256, 0, stream>>>(Wv, Wv_bf, 1048576);
    cast_bf16<<<8192,  256, 0, stream>>>(Wo, Wo_bf, 8388608);

    // qgk = hidden @ [Wq;Wk]^T   (4096 x 8704)
    gemm_bt<1><<<dim3(68, 32), 256, 0, stream>>>(h_bf, Wqk_bf, qgk, 4096, 8704, 2048);
    // v_t = Wv @ hidden^T        (512 x 4096)  == V^T, d-major
    gemm_bt<1><<<dim3(32, 4), 256, 0, stream>>>(Wv_bf, h_bf, v_t, 512, 4096, 2048);

    norm_rope<<<dim3(4096, 18), 64, 0, stream>>>(qgk, cosp, sinp, qw, kw, q_f, k_f);

    attn_fused<<<dim3(512), 256, 0, stream>>>(q_f, k_f, v_t, qgk, attn_g);

    // out = attn_g @ Wo^T        (4096 x 2048) fp32
    gemm_bt<0><<<dim3(16, 32), 256, 0, stream>>>(attn_g, Wo_bf, out, 4096, 2048, 4096);
}

// Round 5
// 694.315 us; speedup vs baseline: 1.1335x; 1.1335x over previous
//
#include <hip/hip_runtime.h>
#include <stdint.h>

typedef unsigned short u16;
typedef __bf16 bf16x8 __attribute__((ext_vector_type(8)));
typedef float f32x4 __attribute__((ext_vector_type(4)));
typedef u16 u16x4 __attribute__((ext_vector_type(4)));
typedef u16 u16x8 __attribute__((ext_vector_type(8)));

__device__ __forceinline__ u16 f2b(float f) {  // fp32 -> bf16 bits, RNE
    unsigned u = __builtin_bit_cast(unsigned, f);
    u = u + 0x7FFFu + ((u >> 16) & 1u);
    return (u16)(u >> 16);
}
__device__ __forceinline__ float b2f(u16 b) {
    return __builtin_bit_cast(float, (unsigned)b << 16);
}

// async global->LDS, 16B per lane. LDS dest = wave-uniform base + lane*16.
// Global source address is per-lane — exploited for XOR-swizzled stores.
__device__ __forceinline__ void glds16(const u16* g, u16* l) {
    __builtin_amdgcn_global_load_lds(
        (const __attribute__((address_space(1))) void*)g,
        (__attribute__((address_space(3))) void*)l,
        16, 0, 0);
}

// ---------------------------------------------------------------- cast fp32->bf16
__global__ __launch_bounds__(256) void cast_bf16(const float* __restrict__ src,
                                                 u16* __restrict__ dst, int n) {
    int i = (blockIdx.x * 256 + threadIdx.x) * 4;
    if (i >= n) return;
    f32x4 v = *(const f32x4*)(src + i);
    u16x4 o;
    o.x = f2b(v.x); o.y = f2b(v.y); o.z = f2b(v.z); o.w = f2b(v.w);
    *(u16x4*)(dst + i) = o;
}

// ---------------------------------------------------------------- GEMM C = A * Bt^T
// 128x128 tile, BK=32, 256 threads (4 waves, each 64x64 = 4x4 mfma 16x16x32).
template <int OUT_BF16>
__global__ __launch_bounds__(256) void gemm_bt(const u16* __restrict__ A,
                                               const u16* __restrict__ Bt,
                                               void* __restrict__ Cout,
                                               int M, int N, int K) {
    __shared__ u16 As[128 * 32];
    __shared__ u16 Bs[128 * 32];
    const int tid  = threadIdx.x;
    const int w    = tid >> 6;
    const int lane = tid & 63;
    const int quad = lane >> 4;
    const int ml   = lane & 15;
    const long bm  = (long)blockIdx.y * 128;
    const long bn  = (long)blockIdx.x * 128;
    const int wm   = (w >> 1) * 64;
    const int wn   = (w & 1) * 64;
    const int grow = lane >> 2;        // 0..15
    const int gcol = (lane & 3) * 8;   // 0,8,16,24

    const u16* Ag = A  + (bm + w * 16 + grow) * (long)K + gcol;
    const u16* Bg = Bt + (bn + w * 16 + grow) * (long)K + gcol;
    u16* lAs0 = &As[(w * 16) * 32];
    u16* lAs1 = &As[(64 + w * 16) * 32];
    u16* lBs0 = &Bs[(w * 16) * 32];
    u16* lBs1 = &Bs[(64 + w * 16) * 32];

    const f32x4 fz = {0.f, 0.f, 0.f, 0.f};
    f32x4 acc[4][4];
#pragma unroll
    for (int i = 0; i < 4; ++i)
#pragma unroll
        for (int j = 0; j < 4; ++j) acc[i][j] = fz;

    for (int k0 = 0; k0 < K; k0 += 32) {
        __syncthreads();
        glds16(Ag + k0,               lAs0);
        glds16(Ag + 64 * (long)K + k0, lAs1);
        glds16(Bg + k0,               lBs0);
        glds16(Bg + 64 * (long)K + k0, lBs1);
        __builtin_amdgcn_s_waitcnt(0);
        __syncthreads();
        bf16x8 af[4], bfr[4];
#pragma unroll
        for (int mt = 0; mt < 4; ++mt)
            af[mt] = *(const bf16x8*)&As[(wm + mt * 16 + ml) * 32 + quad * 8];
#pragma unroll
        for (int nt = 0; nt < 4; ++nt)
            bfr[nt] = *(const bf16x8*)&Bs[(wn + nt * 16 + ml) * 32 + quad * 8];
#pragma unroll
        for (int mt = 0; mt < 4; ++mt)
#pragma unroll
            for (int nt = 0; nt < 4; ++nt)
                acc[mt][nt] = __builtin_amdgcn_mfma_f32_16x16x32_bf16(
                    af[mt], bfr[nt], acc[mt][nt], 0, 0, 0);
    }
#pragma unroll
    for (int mt = 0; mt < 4; ++mt)
#pragma unroll
        for (int nt = 0; nt < 4; ++nt)
#pragma unroll
            for (int r = 0; r < 4; ++r) {
                long row = bm + wm + mt * 16 + quad * 4 + r;
                long col = bn + wn + nt * 16 + ml;
                float v = acc[mt][nt][r];
                if (OUT_BF16) ((u16*)Cout)[row * N + col] = f2b(v);
                else          ((float*)Cout)[row * N + col] = v;
            }
}

// ---------------------------------------------------------------- RMSNorm + RoPE + relayout
// q output pre-scaled by 1/sqrt(HEAD_DIM) = 2^-4 (exact in bf16).
__global__ __launch_bounds__(64) void norm_rope(const u16* __restrict__ qgk,
                                                const float* __restrict__ cosp,
                                                const float* __restrict__ sinp,
                                                const float* __restrict__ qw,
                                                const float* __restrict__ kw,
                                                u16* __restrict__ qf,
                                                u16* __restrict__ kf) {
    const int t = blockIdx.x;      // token = b*2048 + s
    const int u = blockIdx.y;
    const int lane = threadIdx.x;
    const int b = t >> 11, s = t & 2047;
    const u16* src; const float* wgt; u16* dst;
    if (u < 16) {
        src = qgk + (long)t * 8704 + u * 512;
        wgt = qw;
        dst = qf + ((long)(b * 16 + u) * 2048 + s) * 256;
    } else {
        int kh = u - 16;
        src = qgk + (long)t * 8704 + 8192 + kh * 256;
        wgt = kw;
        dst = kf + ((long)(b * 2 + kh) * 2048 + s) * 256;
    }
    const int d0 = lane * 4;
    u16x4 raw = *(const u16x4*)(src + d0);
    float x0 = b2f(raw.x), x1 = b2f(raw.y), x2 = b2f(raw.z), x3 = b2f(raw.w);
    float ss = x0 * x0 + x1 * x1 + x2 * x2 + x3 * x3;
    for (int off = 32; off; off >>= 1) ss += __shfl_xor(ss, off, 64);
    float inv = rsqrtf(ss * (1.0f / 256.0f) + 1e-6f);
    float n0 = x0 * inv * wgt[d0 + 0];
    float n1 = x1 * inv * wgt[d0 + 1];
    float n2 = x2 * inv * wgt[d0 + 2];
    float n3 = x3 * inv * wgt[d0 + 3];
    float p0 = __shfl_xor(n0, 8, 64);
    float p1 = __shfl_xor(n1, 8, 64);
    float p2 = __shfl_xor(n2, 8, 64);
    float p3 = __shfl_xor(n3, 8, 64);
    if (lane < 16) {
        f32x4 c  = *(const f32x4*)(cosp + (long)t * 64 + d0);
        f32x4 sn = *(const f32x4*)(sinp + (long)t * 64 + d0);
        float sgn = (lane < 8) ? -1.f : 1.f;
        n0 = n0 * c[0] + sgn * p0 * sn[0];
        n1 = n1 * c[1] + sgn * p1 * sn[1];
        n2 = n2 * c[2] + sgn * p2 * sn[2];
        n3 = n3 * c[3] + sgn * p3 * sn[3];
    }
    const float qs = (u < 16) ? 0.0625f : 1.0f;  // fold 1/sqrt(256) into q
    n0 *= qs; n1 *= qs; n2 *= qs; n3 *= qs;
    u16x4 o;
    o.x = f2b(n0); o.y = f2b(n1); o.z = f2b(n2); o.w = f2b(n3);
    *(u16x4*)(dst + d0) = o;
}

// ---------------------------------------------------------------- flash attention + gate
// Block = 128 q-rows (4 waves x 32 rows), 64-key tiles, fixed-shift softmax.
// Streaming Q (reloaded from L2 each k-tile, 16-reg pipeline) keeps peak
// register demand ~200 -> no spills at the 2-waves/EU 256-reg cap.
// CU pairing: blocks i and i+256 co-reside; they get q-tiles 15-g and g so
// every CU's total work is exactly 34 k-tiles.
__global__ __launch_bounds__(256, 2) void attn_fused(const u16* __restrict__ qf,
                                                     const u16* __restrict__ kf,
                                                     const u16* __restrict__ vt,
                                                     const u16* __restrict__ qgk,
                                                     u16* __restrict__ attn_g) {
    __shared__ u16 Ks[64 * 256];   // [key][d], 512B rows, swizzled, 32 KB
    __shared__ u16 Vt[256 * 64];   // [d][key], 128B rows, swizzled, 32 KB
    u16* Pb = Ks;                  // P: 128 rows x 88 u16 = 22.5 KB, overlaps Ks
    const int idx  = blockIdx.x & 255;
    const int half = blockIdx.x >> 8;
    const int g    = idx >> 5;           // 0..7
    const int h    = idx & 15;
    const int b    = (idx >> 4) & 1;
    const int qt   = half ? g : 15 - g;  // pair qt with 15-qt on one CU
    const int kh = h >> 3;               // GQA rep = 8
    const int tid = threadIdx.x;
    const int w = tid >> 6, lane = tid & 63;
    const int quad = lane >> 4, ml = lane & 15;
    const int qbase = qt * 128;

    // wave's Q base: rows qbase + w*32 + {0,16} + ml, cols dd*32 + quad*8
    const u16* qp_base = qf + ((long)(b * 16 + h) * 2048 + qbase + w * 32 + ml) * 256
                            + quad * 8;

    const f32x4 fz = {0.f, 0.f, 0.f, 0.f};
    f32x4 oacc[2][16];
#pragma unroll
    for (int mt = 0; mt < 2; ++mt)
#pragma unroll
        for (int i = 0; i < 16; ++i) oacc[mt][i] = fz;
    float lsum[2][4] = {{0.f,0.f,0.f,0.f},{0.f,0.f,0.f,0.f}};

    const u16* kbp = kf + (long)(b * 2 + kh) * 2048 * 256;
    const long vbase = (long)kh * 256 * 4096 + (long)b * 2048;

    const int nkt = 2 * qt + 2;  // causal: 64-key tiles 0..2qt+1
    for (int kt = 0; kt < nkt; ++kt) {
        const int kb = kt * 64;
        __syncthreads();   // prev iter's P/Vt reads complete everywhere
        // ---- stage K and V (each wave: 8 K-segments + 8 V-segments of 1 KB)
#pragma unroll
        for (int i = 0; i < 8; ++i) {
            int s = w * 8 + i;
            {   // K segment s: local keys 2s, 2s+1
                int keyl = 2 * s + (lane >> 5);
                int c = (lane & 31) ^ (keyl & 7);
                glds16(kbp + (long)(kb + keyl) * 256 + c * 8, &Ks[s * 512]);
            }
            {   // V segment s: d rows 8s..8s+7
                int dl = 8 * s + (lane >> 3);
                int c = (lane & 7) ^ (dl & 7);
                glds16(vt + vbase + (long)dl * 4096 + kb + c * 8, &Vt[s * 512]);
            }
        }
        __builtin_amdgcn_s_waitcnt(0);
        __syncthreads();   // tiles visible

        // ---- S = Q K^T with streaming Q (opaque ptr defeats LICM re-hoist)
        const u16* qp = qp_base;
        asm volatile("" : "+v"(qp));
        f32x4 sacc[2][4];
#pragma unroll
        for (int mt = 0; mt < 2; ++mt)
#pragma unroll
            for (int nt = 0; nt < 4; ++nt) sacc[mt][nt] = fz;
        bf16x8 q0n = *(const bf16x8*)(qp);
        bf16x8 q1n = *(const bf16x8*)(qp + 16 * 256);
#pragma unroll
        for (int dd = 0; dd < 8; ++dd) {
            bf16x8 q0 = q0n, q1 = q1n;
            if (dd < 7) {
                q0n = *(const bf16x8*)(qp + (dd + 1) * 32);
                q1n = *(const bf16x8*)(qp + 16 * 256 + (dd + 1) * 32);
            }
#pragma unroll
            for (int nt = 0; nt < 4; ++nt) {
                bf16x8 kfr = *(const bf16x8*)&Ks[(nt * 16 + ml) * 256 +
                                                 (((dd * 4 + quad) ^ (ml & 7)) * 8)];
                sacc[0][nt] = __builtin_amdgcn_mfma_f32_16x16x32_bf16(q0, kfr, sacc[0][nt], 0, 0, 0);
                sacc[1][nt] = __builtin_amdgcn_mfma_f32_16x16x32_bf16(q1, kfr, sacc[1][nt], 0, 0, 0);
            }
        }
        __syncthreads();   // ALL waves done reading Ks before P overwrites it

        // ---- fixed-shift softmax: p = exp(s-16); |s|<=16 by RMS-norm construction
#pragma unroll
        for (int mt = 0; mt < 2; ++mt) {
            const int base_mt = qbase + w * 32 + mt * 16;
            const int prow = (w * 32 + mt * 16 + quad * 4) * 88;
            if (kb + 63 > base_mt) {   // tile touches/crosses the diagonal
#pragma unroll
                for (int nt = 0; nt < 4; ++nt)
#pragma unroll
                    for (int r = 0; r < 4; ++r) {
                        int col = kb + nt * 16 + ml;
                        int row = base_mt + quad * 4 + r;
                        float sv = (col > row) ? -1e30f : sacc[mt][nt][r];
                        float pv = __expf(sv - 16.0f);
                        lsum[mt][r] += pv;
                        Pb[prow + r * 88 + nt * 16 + ml] = f2b(pv);
                    }
            } else {
#pragma unroll
                for (int nt = 0; nt < 4; ++nt)
#pragma unroll
                    for (int r = 0; r < 4; ++r) {
                        float pv = __expf(sacc[mt][nt][r] - 16.0f);
                        lsum[mt][r] += pv;
                        Pb[prow + r * 88 + nt * 16 + ml] = f2b(pv);
                    }
            }
        }

        // ---- O += P V  (P rows wave-private; Vt stable until next stage)
#pragma unroll
        for (int ks = 0; ks < 2; ++ks) {
            bf16x8 pf0 = *(const bf16x8*)&Pb[(w * 32 + ml) * 88 + ks * 32 + quad * 8];
            bf16x8 pf1 = *(const bf16x8*)&Pb[(w * 32 + 16 + ml) * 88 + ks * 32 + quad * 8];
#pragma unroll
            for (int dt = 0; dt < 16; ++dt) {
                bf16x8 vfr = *(const bf16x8*)&Vt[(dt * 16 + ml) * 64 +
                                                 (((ks * 4 + quad) ^ (ml & 7)) * 8)];
                oacc[0][dt] = __builtin_amdgcn_mfma_f32_16x16x32_bf16(pf0, vfr, oacc[0][dt], 0, 0, 0);
                oacc[1][dt] = __builtin_amdgcn_mfma_f32_16x16x32_bf16(pf1, vfr, oacc[1][dt], 0, 0, 0);
            }
        }
    }

    // ---- deferred row-sum reduction (16 lanes of each quad-row group)
#pragma unroll
    for (int off = 1; off < 16; off <<= 1)
#pragma unroll
        for (int mt = 0; mt < 2; ++mt)
#pragma unroll
            for (int r = 0; r < 4; ++r) lsum[mt][r] += __shfl_xor(lsum[mt][r], off, 64);
    float invl[2][4];
#pragma unroll
    for (int mt = 0; mt < 2; ++mt)
#pragma unroll
        for (int r = 0; r < 4; ++r) invl[mt][r] = __builtin_amdgcn_rcpf(lsum[mt][r]);

    // ---- epilogue: sigmoid gate, store bf16 (4096 x 4096, col = h*256+d)
#pragma unroll
    for (int mt = 0; mt < 2; ++mt)
#pragma unroll
        for (int dt = 0; dt < 16; ++dt)
#pragma unroll
            for (int r = 0; r < 4; ++r) {
                int srow = qbase + w * 32 + mt * 16 + quad * 4 + r;
                long tok = (long)b * 2048 + srow;
                int d = dt * 16 + ml;
                float o = oacc[mt][dt][r] * invl[mt][r];
                float g2 = b2f(qgk[tok * 8704 + h * 512 + 256 + d]);
                float gv = o * __builtin_amdgcn_rcpf(1.f + __expf(-g2));
                attn_g[tok * 4096 + h * 256 + d] = f2b(gv);
            }
}

// ---------------------------------------------------------------- launch
extern "C" void kernel_launch(void* const* d_in, const int* in_sizes, int n_in,
                              void* d_out, int out_size, void* d_ws, size_t ws_size,
                              hipStream_t stream) {
    (void)in_sizes; (void)n_in; (void)out_size;
    const float* hidden = (const float*)d_in[0];
    const float* cosp   = (const float*)d_in[1];
    const float* sinp   = (const float*)d_in[2];
    const float* Wq     = (const float*)d_in[3];
    const float* Wk     = (const float*)d_in[4];
    const float* Wv     = (const float*)d_in[5];
    const float* Wo     = (const float*)d_in[6];
    const float* qw     = (const float*)d_in[7];
    const float* kw     = (const float*)d_in[8];
    float* out = (float*)d_out;

    char* p = (char*)d_ws;
    u16* h_bf   = (u16*)p; p += (size_t)8388608 * 2;   // hidden bf16 (4096x2048)
    u16* Wqk_bf = (u16*)p; p += (size_t)17825792 * 2;  // Wq||Wk (8704x2048)
    u16* Wv_bf  = (u16*)p; p += (size_t)1048576 * 2;   // Wv (512x2048)
    u16* Wo_bf  = (u16*)p; p += (size_t)8388608 * 2;   // Wo (2048x4096)
    u16* qgk    = (u16*)p; p += (size_t)35651584 * 2;  // (4096x8704)
    u16* v_t    = (u16*)p; p += (size_t)2097152 * 2;   // V^T (512x4096)
    u16* q_f    = (u16*)p; p += (size_t)16777216 * 2;  // (2,16,2048,256)
    u16* k_f    = (u16*)p; p += (size_t)2097152 * 2;   // (2,2,2048,256)
    u16* attn_g = (u16*)p; p += (size_t)16777216 * 2;  // (4096x4096)
    if ((size_t)(p - (char*)d_ws) > ws_size) return;   // ws too small: leave output zero

    cast_bf16<<<8192,  256, 0, stream>>>(hidden, h_bf, 8388608);
    cast_bf16<<<16384, 256, 0, stream>>>(Wq, Wqk_bf, 16777216);
    cast_bf16<<<1024,  256, 0, stream>>>(Wk, Wqk_bf + (size_t)8192 * 2048, 1048576);
    cast_bf16<<<1024,  256, 0, stream>>>(Wv, Wv_bf, 1048576);
    cast_bf16<<<8192,  256, 0, stream>>>(Wo, Wo_bf, 8388608);

    // qgk = hidden @ [Wq;Wk]^T   (4096 x 8704)
    gemm_bt<1><<<dim3(68, 32), 256, 0, stream>>>(h_bf, Wqk_bf, qgk, 4096, 8704, 2048);
    // v_t = Wv @ hidden^T        (512 x 4096)  == V^T, d-major
    gemm_bt<1><<<dim3(32, 4), 256, 0, stream>>>(Wv_bf, h_bf, v_t, 512, 4096, 2048);

    norm_rope<<<dim3(4096, 18), 64, 0, stream>>>(qgk, cosp, sinp, qw, kw, q_f, k_f);

    attn_fused<<<dim3(512), 256, 0, stream>>>(q_f, k_f, v_t, qgk, attn_g);

    // out = attn_g @ Wo^T        (4096 x 2048) fp32
    gemm_bt<0><<<dim3(16, 32), 256, 0, stream>>>(attn_g, Wo_bf, out, 4096, 2048, 4096);
}